// Round 7
// baseline (204.416 us; speedup 1.0000x reference)
//
#include <hip/hip_runtime.h>
#include <cstdint>
#include <cstddef>

// MMD loss, N=8192 (b=4096), D=512.
//   bw closed form: sum(L2) = 2n*S - 2*||colsum||^2
//   R7: A-STRIP-IN-LDS, B-DIRECT-FROM-L2. Block = strip ti x chunk of 2 tj.
//       A (128 rows, 64KB frag-major contiguous) staged to LDS ONCE (single
//       barrier, then read-only -> no stage/drain lockstep). 4 waves partition
//       N (each 128x32) -> zero B redundancy. L2 traffic 532->200MB,
//       LDS 533MB @52TB/s ~ 10us = new max pipe.
//   R6: fragment-major int8 layout: chunk (rb,c) = 16 rows x 16B contiguous
//       256B block; every fragment load = one coalesced 1KB wave transaction.
//   R4: INT8 MFMA 16x16x64 (scale 1/16, exact int32 acc), diag forced exact.
//   Epilogue: sum_k exp(-L2/(bw*2^k)) = e+e^2+e^4+e^8+e^16, e=exp2(-L2*log2e/(16bw))
//   R2: no single-address atomics (were 107us of serialization).

#define D_DIM 512
#define B_ROWS 4096
#define N_ROWS 8192
#define NTILES 64        // 8192 / 128
#define NBLK_MMD 1056    // sum_ti ceil((64-ti)/2)

typedef __attribute__((ext_vector_type(4))) int i32x4;

#define AS1(p) ((const __attribute__((address_space(1))) void*)(p))
#define AS3(p) ((__attribute__((address_space(3))) void*)(p))

__device__ inline float waveReduce(float v) {
    #pragma unroll
    for (int off = 32; off > 0; off >>= 1) v += __shfl_down(v, off, 64);
    return v;
}

__device__ inline int q8(float x) {
    int v = (int)rintf(x * 16.f);             // RNE; s = 1/16
    v = v > 127 ? 127 : v;
    v = v < -127 ? -127 : v;
    return v & 255;
}

// Fragment-major address: row r, 16B-chunk c (0..31):
//   rb = r>>4, w = r&15;  byte addr = ((rb*32 + c) << 8) + w*16

// ---- K1: per-row sq norms (fp32, exact) + fp32->int8 quantize (frag-major) ----
__global__ __launch_bounds__(256) void k_rowstats(const float* __restrict__ src,
                                                  const float* __restrict__ tgt,
                                                  unsigned char* __restrict__ Tp,
                                                  float* __restrict__ sq) {
    int wave = threadIdx.x >> 6;
    int lane = threadIdx.x & 63;
    int row  = blockIdx.x * 4 + wave;
    const float* base = (row < B_ROWS) ? (src + (size_t)row * D_DIM)
                                       : (tgt + (size_t)(row - B_ROWS) * D_DIM);
    float4 a = ((const float4*)base)[lane * 2];
    float4 b = ((const float4*)base)[lane * 2 + 1];
    uint2 o;   // bytes [8*lane, 8*lane+8) of the quantized row
    o.x = (unsigned)(q8(a.x) | (q8(a.y) << 8) | (q8(a.z) << 16) | (q8(a.w) << 24));
    o.y = (unsigned)(q8(b.x) | (q8(b.y) << 8) | (q8(b.z) << 16) | (q8(b.w) << 24));
    int rb = row >> 4, w = row & 15;
    int c  = lane >> 1, h = lane & 1;
    *(uint2*)(Tp + (((size_t)(rb * 32 + c)) << 8) + w * 16 + h * 8) = o;
    float s = a.x*a.x + a.y*a.y + a.z*a.z + a.w*a.w
            + b.x*b.x + b.y*b.y + b.z*b.z + b.w*b.w;
    s = waveReduce(s);
    if (lane == 0) sq[row] = s;
}

// ---- K2: exact int8 column-sum partials from frag-major layout ----
__global__ __launch_bounds__(256) void k_colsum(const unsigned int* __restrict__ Tu,
                                                int* __restrict__ partial) {
    int t   = threadIdx.x;
    int u   = t & 127;
    int c   = u >> 2, q = u & 3;
    int sub = t >> 7;              // w in [sub*8, sub*8+8)
    int a0 = 0, a1 = 0, a2 = 0, a3 = 0;
    #pragma unroll 2
    for (int j = 0; j < 8; ++j) {
        int rb = blockIdx.x * 8 + j;
        #pragma unroll
        for (int wv = 0; wv < 8; ++wv) {
            int w = sub * 8 + wv;
            unsigned int v = Tu[(size_t)(rb * 32 + c) * 64 + w * 4 + q];
            a0 += (int)(signed char)(v);
            a1 += (int)(signed char)(v >> 8);
            a2 += (int)(signed char)(v >> 16);
            a3 += (int)(signed char)(v >> 24);
        }
    }
    int basep = (blockIdx.x * 2 + sub) * 512 + u * 4;
    partial[basep + 0] = a0;
    partial[basep + 1] = a1;
    partial[basep + 2] = a2;
    partial[basep + 3] = a3;
}

// ---- K3: finalize bandwidth -> c16 = -log2(e)/(16*bw) ----
__global__ __launch_bounds__(512) void k_bw(const int* __restrict__ partial,
                                            const float* __restrict__ sq,
                                            float* __restrict__ c16out) {
    int t = threadIdx.x;
    int csum = 0;
    #pragma unroll 8
    for (int i = 0; i < 128; ++i) csum += partial[i * 512 + t];
    float cs = (float)csum * 0.0625f;          // * s (1/16)
    float p = cs * cs;
    float ssq = 0.f;
    #pragma unroll
    for (int i = 0; i < 16; ++i) ssq += sq[t + i * 512];
    __shared__ float r8[8], q8s[8];
    float wp = waveReduce(p);
    float wq = waveReduce(ssq);
    if ((t & 63) == 0) { r8[t >> 6] = wp; q8s[t >> 6] = wq; }
    __syncthreads();
    if (t == 0) {
        double P = 0.0, Q = 0.0;
        #pragma unroll
        for (int i = 0; i < 8; ++i) { P += r8[i]; Q += q8s[i]; }
        double n = (double)N_ROWS;
        double sumL2 = 2.0 * n * Q - 2.0 * P;
        double bw = sumL2 / (n * n - n) / 4.0;   // / KERNEL_MUL^(NUM/2)
        c16out[0] = (float)(-1.4426950408889634 / (16.0 * bw));
    }
}

// ---- K4: A-strip-in-LDS int8 Gram + fused MMD epilogue ----
// Block: strip ti, chunk of up to 2 tj. One barrier (A staging), then LDS
// read-only. 4 waves partition N: wave w -> cols [w*32, w*32+32), full M=128.
__global__ __launch_bounds__(256, 2) void k_mmd(const unsigned char* __restrict__ Tp,
                                                const float* __restrict__ sq,
                                                const float* __restrict__ c16in,
                                                float* __restrict__ blockpart) {
    // decode (ti, tj0)
    int rem = blockIdx.x, ti = 0;
    for (;;) {
        int nch = (NTILES - ti + 1) >> 1;
        if (rem < nch) break;
        rem -= nch; ti++;
    }
    int tj0 = ti + 2 * rem;
    int ntj = (NTILES - tj0) < 2 ? (NTILES - tj0) : 2;

    int tid  = threadIdx.x;
    int wave = tid >> 6;
    int lane = tid & 63;
    int l15  = lane & 15;
    int quad = lane >> 4;

    __shared__ unsigned char As[65536];   // A strip: 128 rows x 512 B, frag-major
    __shared__ float red[4];

    // stage A strip (contiguous 64 KB in frag-major layout), single barrier
    const unsigned char* Ag = Tp + ((size_t)ti << 16);
    #pragma unroll
    for (int r = 0; r < 16; ++r)
        __builtin_amdgcn_global_load_lds(AS1(Ag + r * 4096 + tid * 16),
                                         AS3(As + r * 4096 + tid * 16), 16, 0, 0);

    float c16 = c16in[0];                    // -log2e/(16 bw)
    float cgq = -2.f * c16 * (1.f / 256.f);  // fold s^2 = 1/256

    // per-lane row coefficients (M = full 128): rl = mi*16 + quad*4 + rr
    float trow[32];
    #pragma unroll
    for (int mi = 0; mi < 8; ++mi)
        #pragma unroll
        for (int rr = 0; rr < 4; ++rr)
            trow[mi * 4 + rr] = sq[ti * 128 + mi * 16 + quad * 4 + rr] * c16;

    __syncthreads();   // A staged (compiler drains vmcnt before barrier)

    float bsum = 0.f;
    for (int t = 0; t < ntj; ++t) {
        int tj = tj0 + t;
        i32x4 acc[8][2];
        #pragma unroll
        for (int mi = 0; mi < 8; ++mi) {
            acc[mi][0] = (i32x4){0, 0, 0, 0};
            acc[mi][1] = (i32x4){0, 0, 0, 0};
        }

        const unsigned char* Bg = Tp + (((size_t)(tj * 8 + wave * 2)) << 13);

        #pragma unroll
        for (int kk = 0; kk < 8; ++kk) {
            int coff = (kk * 4 + quad) * 256 + l15 * 16;
            i32x4 bf0 = *(const i32x4*)(Bg + coff);
            i32x4 bf1 = *(const i32x4*)(Bg + 8192 + coff);
            #pragma unroll
            for (int mi = 0; mi < 8; ++mi) {
                i32x4 af = *(const i32x4*)(As + mi * 8192 + coff);
                acc[mi][0] = __builtin_amdgcn_mfma_i32_16x16x64_i8(af, bf0, acc[mi][0], 0, 0, 0);
                acc[mi][1] = __builtin_amdgcn_mfma_i32_16x16x64_i8(af, bf1, acc[mi][1], 0, 0, 0);
            }
        }

        // epilogue for this tj
        float tcol0 = sq[tj * 128 + wave * 32 + l15] * c16;
        float tcol1 = sq[tj * 128 + wave * 32 + 16 + l15] * c16;
        bool dtile = (ti == tj);
        float psum = 0.f;
        #pragma unroll
        for (int mi = 0; mi < 8; ++mi) {
            #pragma unroll
            for (int ni = 0; ni < 2; ++ni) {
                float tcol = ni ? tcol1 : tcol0;
                int cl = wave * 32 + ni * 16 + l15;
                #pragma unroll
                for (int rr = 0; rr < 4; ++rr) {
                    float g   = (float)acc[mi][ni][rr];   // exact: |G| < 2^24
                    float t16 = __builtin_fmaf(g, cgq, trow[mi * 4 + rr]) + tcol;
                    float e1  = __builtin_amdgcn_exp2f(t16);
                    float e2  = e1 * e1;
                    float e4  = e2 * e2;
                    float e8  = e4 * e4;
                    float e16 = e8 * e8;
                    float ks5 = ((e1 + e2) + (e4 + e8)) + e16;
                    int rl = mi * 16 + quad * 4 + rr;
                    psum += (dtile && rl == cl) ? 5.0f : ks5;   // exact diagonal
                }
            }
        }
        float sgn   = ((ti < 32) == (tj < 32)) ? 1.f : -1.f;
        float scale = dtile ? sgn : 2.f * sgn;
        bsum += scale * psum;
    }

    float w = waveReduce(bsum);
    if (lane == 0) red[wave] = w;
    __syncthreads();
    if (tid == 0)
        blockpart[blockIdx.x] = red[0] + red[1] + red[2] + red[3];
}

// ---- K5: reduce block partials -> final scalar ----
__global__ __launch_bounds__(256) void k_final(const float* __restrict__ bp,
                                               float* __restrict__ out) {
    int t = threadIdx.x;
    float s = 0.f;
    for (int i = t; i < NBLK_MMD; i += 256) s += bp[i];
    __shared__ float r4[4];
    float w = waveReduce(s);
    if ((t & 63) == 0) r4[t >> 6] = w;
    __syncthreads();
    if (t == 0)
        out[0] = (r4[0] + r4[1] + r4[2] + r4[3]) * (1.f / (4096.f * 4096.f));
}

extern "C" void kernel_launch(void* const* d_in, const int* in_sizes, int n_in,
                              void* d_out, int out_size, void* d_ws, size_t ws_size,
                              hipStream_t stream) {
    const float* src = (const float*)d_in[0];
    const float* tgt = (const float*)d_in[1];

    uint8_t* ws = (uint8_t*)d_ws;
    unsigned char* Tp = (unsigned char*)ws;                    // 4,194,304 B
    size_t off = 4194304;
    float* sq      = (float*)(ws + off); off += 32768;         // 8192 f
    int*   partial = (int*)  (ws + off); off += 128 * 512 * 4; // 256 KB
    float* bp      = (float*)(ws + off); off += 4352;          // 1056 f (padded)
    float* c16     = (float*)(ws + off);

    k_rowstats<<<2048, 256, 0, stream>>>(src, tgt, Tp, sq);
    k_colsum  <<<64, 256, 0, stream>>>((const unsigned int*)Tp, partial);
    k_bw      <<<1, 512, 0, stream>>>(partial, sq, c16);
    k_mmd     <<<NBLK_MMD, 256, 0, stream>>>(Tp, sq, c16, bp);
    k_final   <<<1, 256, 0, stream>>>(bp, (float*)d_out);
}

// Round 8
// 125.119 us; speedup vs baseline: 1.6338x; 1.6338x over previous
//
#include <hip/hip_runtime.h>
#include <cstdint>
#include <cstddef>

// MMD loss, N=8192 (b=4096), D=512.
//   bw closed form: sum(L2) = 2n*S - 2*||colsum||^2
//   R8: R7's A-strip-in-LDS traffic shape with R6's proven register shape.
//       R7 spilled (acc[8][2]+trow[32] -> WRITE_SIZE 166MB of scratch).
//       Now: 2x2 wave grid, acc[4][4] per wave (R6 profile, 76 VGPR no
//       spill), A frags from 64KB LDS strip staged ONCE, B frags direct
//       from L2 (frag-major 1KB coalesced), 2 tj per block.
//   R6: fragment-major int8 layout: chunk (rb,c) = 16 rows x 16B as one
//       contiguous 256B block; fragment load = one 1KB wave transaction.
//   R4: INT8 MFMA 16x16x64 (scale 1/16, exact int32 acc), diag forced exact.
//   Epilogue: sum_k exp(-L2/(bw*2^k)) = e+e^2+e^4+e^8+e^16, e=exp2(-L2*log2e/(16bw))
//   R2: no single-address atomics (were 107us of serialization).

#define D_DIM 512
#define B_ROWS 4096
#define N_ROWS 8192
#define NTILES 64        // 8192 / 128
#define NBLK_MMD 1056    // sum_ti ceil((64-ti)/2)

typedef __attribute__((ext_vector_type(4))) int i32x4;

#define AS1(p) ((const __attribute__((address_space(1))) void*)(p))
#define AS3(p) ((__attribute__((address_space(3))) void*)(p))

__device__ inline float waveReduce(float v) {
    #pragma unroll
    for (int off = 32; off > 0; off >>= 1) v += __shfl_down(v, off, 64);
    return v;
}

__device__ inline int q8(float x) {
    int v = (int)rintf(x * 16.f);             // RNE; s = 1/16
    v = v > 127 ? 127 : v;
    v = v < -127 ? -127 : v;
    return v & 255;
}

// Fragment-major address: row r, 16B-chunk c (0..31):
//   rb = r>>4, w = r&15;  byte addr = ((rb*32 + c) << 8) + w*16

// ---- K1: per-row sq norms (fp32, exact) + fp32->int8 quantize (frag-major) ----
__global__ __launch_bounds__(256) void k_rowstats(const float* __restrict__ src,
                                                  const float* __restrict__ tgt,
                                                  unsigned char* __restrict__ Tp,
                                                  float* __restrict__ sq) {
    int wave = threadIdx.x >> 6;
    int lane = threadIdx.x & 63;
    int row  = blockIdx.x * 4 + wave;
    const float* base = (row < B_ROWS) ? (src + (size_t)row * D_DIM)
                                       : (tgt + (size_t)(row - B_ROWS) * D_DIM);
    float4 a = ((const float4*)base)[lane * 2];
    float4 b = ((const float4*)base)[lane * 2 + 1];
    uint2 o;   // bytes [8*lane, 8*lane+8) of the quantized row
    o.x = (unsigned)(q8(a.x) | (q8(a.y) << 8) | (q8(a.z) << 16) | (q8(a.w) << 24));
    o.y = (unsigned)(q8(b.x) | (q8(b.y) << 8) | (q8(b.z) << 16) | (q8(b.w) << 24));
    int rb = row >> 4, w = row & 15;
    int c  = lane >> 1, h = lane & 1;
    *(uint2*)(Tp + (((size_t)(rb * 32 + c)) << 8) + w * 16 + h * 8) = o;
    float s = a.x*a.x + a.y*a.y + a.z*a.z + a.w*a.w
            + b.x*b.x + b.y*b.y + b.z*b.z + b.w*b.w;
    s = waveReduce(s);
    if (lane == 0) sq[row] = s;
}

// ---- K2: exact int8 column-sum partials from frag-major layout ----
__global__ __launch_bounds__(256) void k_colsum(const unsigned int* __restrict__ Tu,
                                                int* __restrict__ partial) {
    int t   = threadIdx.x;
    int u   = t & 127;
    int c   = u >> 2, q = u & 3;
    int sub = t >> 7;              // w in [sub*8, sub*8+8)
    int a0 = 0, a1 = 0, a2 = 0, a3 = 0;
    #pragma unroll 2
    for (int j = 0; j < 8; ++j) {
        int rb = blockIdx.x * 8 + j;
        #pragma unroll
        for (int wv = 0; wv < 8; ++wv) {
            int w = sub * 8 + wv;
            unsigned int v = Tu[(size_t)(rb * 32 + c) * 64 + w * 4 + q];
            a0 += (int)(signed char)(v);
            a1 += (int)(signed char)(v >> 8);
            a2 += (int)(signed char)(v >> 16);
            a3 += (int)(signed char)(v >> 24);
        }
    }
    int basep = (blockIdx.x * 2 + sub) * 512 + u * 4;
    partial[basep + 0] = a0;
    partial[basep + 1] = a1;
    partial[basep + 2] = a2;
    partial[basep + 3] = a3;
}

// ---- K3: finalize bandwidth -> c16 = -log2(e)/(16*bw) ----
__global__ __launch_bounds__(512) void k_bw(const int* __restrict__ partial,
                                            const float* __restrict__ sq,
                                            float* __restrict__ c16out) {
    int t = threadIdx.x;
    int csum = 0;
    #pragma unroll 8
    for (int i = 0; i < 128; ++i) csum += partial[i * 512 + t];
    float cs = (float)csum * 0.0625f;          // * s (1/16)
    float p = cs * cs;
    float ssq = 0.f;
    #pragma unroll
    for (int i = 0; i < 16; ++i) ssq += sq[t + i * 512];
    __shared__ float r8[8], q8s[8];
    float wp = waveReduce(p);
    float wq = waveReduce(ssq);
    if ((t & 63) == 0) { r8[t >> 6] = wp; q8s[t >> 6] = wq; }
    __syncthreads();
    if (t == 0) {
        double P = 0.0, Q = 0.0;
        #pragma unroll
        for (int i = 0; i < 8; ++i) { P += r8[i]; Q += q8s[i]; }
        double n = (double)N_ROWS;
        double sumL2 = 2.0 * n * Q - 2.0 * P;
        double bw = sumL2 / (n * n - n) / 4.0;   // / KERNEL_MUL^(NUM/2)
        c16out[0] = (float)(-1.4426950408889634 / (16.0 * bw));
    }
}

// ---- K4: A-strip-in-LDS int8 Gram + fused MMD epilogue (R6 register shape) ----
__global__ __launch_bounds__(256) void k_mmd(const unsigned char* __restrict__ Tp,
                                             const float* __restrict__ sq,
                                             const float* __restrict__ c16in,
                                             float* __restrict__ blockpart) {
    // decode (ti, tj0): chunks of up to 2 tj per strip ti
    int rem = blockIdx.x, ti = 0;
    for (;;) {
        int nch = (NTILES - ti + 1) >> 1;
        if (rem < nch) break;
        rem -= nch; ti++;
    }
    int tj0 = ti + 2 * rem;
    int ntj = (NTILES - tj0) < 2 ? (NTILES - tj0) : 2;

    int tid  = threadIdx.x;
    int wave = tid >> 6;
    int lane = tid & 63;
    int waveM = (wave >> 1) * 64;    // A rows half
    int waveN = (wave & 1) * 64;     // B cols half
    int l15  = lane & 15;
    int quad = lane >> 4;

    __shared__ unsigned char As[65536];   // A strip: 128 rows, frag-major
    __shared__ float red[4];

    // stage A strip (contiguous 64 KB in frag-major layout), single barrier
    const unsigned char* Ag = Tp + ((size_t)ti << 16);
    #pragma unroll
    for (int r = 0; r < 16; ++r)
        __builtin_amdgcn_global_load_lds(AS1(Ag + r * 4096 + tid * 16),
                                         AS3(As + r * 4096 + tid * 16), 16, 0, 0);

    float c16 = c16in[0];                    // -log2e/(16 bw)
    float cgq = -2.f * c16 * (1.f / 256.f);  // fold s^2 = 1/256

    // per-lane A-row coefficients for this wave's M half (16 regs, as R6)
    const float* sqA = sq + ti * 128;
    float trow16[16];
    #pragma unroll
    for (int mi = 0; mi < 4; ++mi)
        #pragma unroll
        for (int rr = 0; rr < 4; ++rr)
            trow16[mi * 4 + rr] = sqA[waveM + mi * 16 + quad * 4 + rr] * c16;

    __syncthreads();   // A staged

    int rbA = (wave >> 1) * 4;       // local A row-block base in LDS

    float bsum = 0.f;
    for (int t = 0; t < ntj; ++t) {
        int tj = tj0 + t;
        i32x4 acc[4][4];
        #pragma unroll
        for (int mi = 0; mi < 4; ++mi)
            #pragma unroll
            for (int ni = 0; ni < 4; ++ni)
                acc[mi][ni] = (i32x4){0, 0, 0, 0};

        const unsigned char* Bg = Tp + (((size_t)(tj * 8 + (wave & 1) * 4)) << 13);

        #pragma unroll
        for (int kk = 0; kk < 8; ++kk) {
            int coff = (kk * 4 + quad) * 256 + l15 * 16;
            i32x4 af[4], bf[4];
            #pragma unroll
            for (int mi = 0; mi < 4; ++mi)
                af[mi] = *(const i32x4*)(As + (rbA + mi) * 8192 + coff);
            #pragma unroll
            for (int ni = 0; ni < 4; ++ni)
                bf[ni] = *(const i32x4*)(Bg + ((size_t)ni << 13) + coff);
            #pragma unroll
            for (int mi = 0; mi < 4; ++mi)
                #pragma unroll
                for (int ni = 0; ni < 4; ++ni)
                    acc[mi][ni] = __builtin_amdgcn_mfma_i32_16x16x64_i8(
                        af[mi], bf[ni], acc[mi][ni], 0, 0, 0);
        }

        // epilogue for this tj
        const float* sqB = sq + tj * 128;
        float tcol16[4];
        #pragma unroll
        for (int ni = 0; ni < 4; ++ni)
            tcol16[ni] = sqB[waveN + ni * 16 + l15] * c16;

        bool dtile = (ti == tj);
        float psum = 0.f;
        #pragma unroll
        for (int mi = 0; mi < 4; ++mi) {
            #pragma unroll
            for (int ni = 0; ni < 4; ++ni) {
                int cl = waveN + ni * 16 + l15;
                #pragma unroll
                for (int rr = 0; rr < 4; ++rr) {
                    float g   = (float)acc[mi][ni][rr];   // exact: |G| < 2^24
                    float t16 = __builtin_fmaf(g, cgq, trow16[mi * 4 + rr]) + tcol16[ni];
                    float e1  = __builtin_amdgcn_exp2f(t16);
                    float e2  = e1 * e1;
                    float e4  = e2 * e2;
                    float e8  = e4 * e4;
                    float e16 = e8 * e8;
                    float ks5 = ((e1 + e2) + (e4 + e8)) + e16;
                    int rl = waveM + mi * 16 + quad * 4 + rr;
                    psum += (dtile && rl == cl) ? 5.0f : ks5;   // exact diagonal
                }
            }
        }
        float sgn   = ((ti < 32) == (tj < 32)) ? 1.f : -1.f;
        float scale = dtile ? sgn : 2.f * sgn;
        bsum += scale * psum;
    }

    float w = waveReduce(bsum);
    if (lane == 0) red[wave] = w;
    __syncthreads();
    if (tid == 0)
        blockpart[blockIdx.x] = red[0] + red[1] + red[2] + red[3];
}

// ---- K5: reduce block partials -> final scalar ----
__global__ __launch_bounds__(256) void k_final(const float* __restrict__ bp,
                                               float* __restrict__ out) {
    int t = threadIdx.x;
    float s = 0.f;
    for (int i = t; i < NBLK_MMD; i += 256) s += bp[i];
    __shared__ float r4[4];
    float w = waveReduce(s);
    if ((t & 63) == 0) r4[t >> 6] = w;
    __syncthreads();
    if (t == 0)
        out[0] = (r4[0] + r4[1] + r4[2] + r4[3]) * (1.f / (4096.f * 4096.f));
}

extern "C" void kernel_launch(void* const* d_in, const int* in_sizes, int n_in,
                              void* d_out, int out_size, void* d_ws, size_t ws_size,
                              hipStream_t stream) {
    const float* src = (const float*)d_in[0];
    const float* tgt = (const float*)d_in[1];

    uint8_t* ws = (uint8_t*)d_ws;
    unsigned char* Tp = (unsigned char*)ws;                    // 4,194,304 B
    size_t off = 4194304;
    float* sq      = (float*)(ws + off); off += 32768;         // 8192 f
    int*   partial = (int*)  (ws + off); off += 128 * 512 * 4; // 256 KB
    float* bp      = (float*)(ws + off); off += 4352;          // 1056 f (padded)
    float* c16     = (float*)(ws + off);

    k_rowstats<<<2048, 256, 0, stream>>>(src, tgt, Tp, sq);
    k_colsum  <<<64, 256, 0, stream>>>((const unsigned int*)Tp, partial);
    k_bw      <<<1, 512, 0, stream>>>(partial, sq, c16);
    k_mmd     <<<NBLK_MMD, 256, 0, stream>>>(Tp, sq, c16, bp);
    k_final   <<<1, 256, 0, stream>>>(bp, (float*)d_out);
}

// Round 9
// 121.493 us; speedup vs baseline: 1.6825x; 1.0298x over previous
//
#include <hip/hip_runtime.h>
#include <cstdint>
#include <cstddef>

// MMD loss, N=8192 (b=4096), D=512.
//   bw closed form: sum(L2) = 2n*S - 2*||colsum||^2
//   R9: EXPLICIT REGISTER PREFETCH in k_mmd's K-loop. R8 was latency-bound
//       (MfmaUtil 12%, Occ 8.3%: 2 waves/SIMD from 64KB LDS, and each kk's
//       16 MFMAs waited on that kk's 4 L2 + 4 LDS loads). Now kk+1 fragments
//       load into afn/bfn BEFORE kk's MFMAs issue; 326 SIMD-cyc of MFMA per
//       iteration hides the ~200cyc L2 latency. VGPR ~176 is free (LDS caps
//       occupancy anyway). Same traffic shape as R8 (A strip in LDS staged
//       once, B direct from L2, frag-major 1KB coalesced loads).
//   R6: fragment-major int8 layout: chunk (rb,c) = 16 rows x 16B as one
//       contiguous 256B block; fragment load = one 1KB wave transaction.
//   R4: INT8 MFMA 16x16x64 (scale 1/16, exact int32 acc), diag forced exact.
//   Epilogue: sum_k exp(-L2/(bw*2^k)) = e+e^2+e^4+e^8+e^16, e=exp2(-L2*log2e/(16bw))
//   R2: no single-address atomics (were 107us of serialization).

#define D_DIM 512
#define B_ROWS 4096
#define N_ROWS 8192
#define NTILES 64        // 8192 / 128
#define NBLK_MMD 1056    // sum_ti ceil((64-ti)/2)

typedef __attribute__((ext_vector_type(4))) int i32x4;

#define AS1(p) ((const __attribute__((address_space(1))) void*)(p))
#define AS3(p) ((__attribute__((address_space(3))) void*)(p))

__device__ inline float waveReduce(float v) {
    #pragma unroll
    for (int off = 32; off > 0; off >>= 1) v += __shfl_down(v, off, 64);
    return v;
}

__device__ inline int q8(float x) {
    int v = (int)rintf(x * 16.f);             // RNE; s = 1/16
    v = v > 127 ? 127 : v;
    v = v < -127 ? -127 : v;
    return v & 255;
}

// Fragment-major address: row r, 16B-chunk c (0..31):
//   rb = r>>4, w = r&15;  byte addr = ((rb*32 + c) << 8) + w*16

// ---- K1: per-row sq norms (fp32, exact) + fp32->int8 quantize (frag-major) ----
__global__ __launch_bounds__(256) void k_rowstats(const float* __restrict__ src,
                                                  const float* __restrict__ tgt,
                                                  unsigned char* __restrict__ Tp,
                                                  float* __restrict__ sq) {
    int wave = threadIdx.x >> 6;
    int lane = threadIdx.x & 63;
    int row  = blockIdx.x * 4 + wave;
    const float* base = (row < B_ROWS) ? (src + (size_t)row * D_DIM)
                                       : (tgt + (size_t)(row - B_ROWS) * D_DIM);
    float4 a = ((const float4*)base)[lane * 2];
    float4 b = ((const float4*)base)[lane * 2 + 1];
    uint2 o;   // bytes [8*lane, 8*lane+8) of the quantized row
    o.x = (unsigned)(q8(a.x) | (q8(a.y) << 8) | (q8(a.z) << 16) | (q8(a.w) << 24));
    o.y = (unsigned)(q8(b.x) | (q8(b.y) << 8) | (q8(b.z) << 16) | (q8(b.w) << 24));
    int rb = row >> 4, w = row & 15;
    int c  = lane >> 1, h = lane & 1;
    *(uint2*)(Tp + (((size_t)(rb * 32 + c)) << 8) + w * 16 + h * 8) = o;
    float s = a.x*a.x + a.y*a.y + a.z*a.z + a.w*a.w
            + b.x*b.x + b.y*b.y + b.z*b.z + b.w*b.w;
    s = waveReduce(s);
    if (lane == 0) sq[row] = s;
}

// ---- K2: exact int8 column-sum partials from frag-major layout ----
__global__ __launch_bounds__(256) void k_colsum(const unsigned int* __restrict__ Tu,
                                                int* __restrict__ partial) {
    int t   = threadIdx.x;
    int u   = t & 127;
    int c   = u >> 2, q = u & 3;
    int sub = t >> 7;              // w in [sub*8, sub*8+8)
    int a0 = 0, a1 = 0, a2 = 0, a3 = 0;
    #pragma unroll 2
    for (int j = 0; j < 8; ++j) {
        int rb = blockIdx.x * 8 + j;
        #pragma unroll
        for (int wv = 0; wv < 8; ++wv) {
            int w = sub * 8 + wv;
            unsigned int v = Tu[(size_t)(rb * 32 + c) * 64 + w * 4 + q];
            a0 += (int)(signed char)(v);
            a1 += (int)(signed char)(v >> 8);
            a2 += (int)(signed char)(v >> 16);
            a3 += (int)(signed char)(v >> 24);
        }
    }
    int basep = (blockIdx.x * 2 + sub) * 512 + u * 4;
    partial[basep + 0] = a0;
    partial[basep + 1] = a1;
    partial[basep + 2] = a2;
    partial[basep + 3] = a3;
}

// ---- K3: finalize bandwidth -> c16 = -log2(e)/(16*bw) ----
__global__ __launch_bounds__(512) void k_bw(const int* __restrict__ partial,
                                            const float* __restrict__ sq,
                                            float* __restrict__ c16out) {
    int t = threadIdx.x;
    int csum = 0;
    #pragma unroll 8
    for (int i = 0; i < 128; ++i) csum += partial[i * 512 + t];
    float cs = (float)csum * 0.0625f;          // * s (1/16)
    float p = cs * cs;
    float ssq = 0.f;
    #pragma unroll
    for (int i = 0; i < 16; ++i) ssq += sq[t + i * 512];
    __shared__ float r8[8], q8s[8];
    float wp = waveReduce(p);
    float wq = waveReduce(ssq);
    if ((t & 63) == 0) { r8[t >> 6] = wp; q8s[t >> 6] = wq; }
    __syncthreads();
    if (t == 0) {
        double P = 0.0, Q = 0.0;
        #pragma unroll
        for (int i = 0; i < 8; ++i) { P += r8[i]; Q += q8s[i]; }
        double n = (double)N_ROWS;
        double sumL2 = 2.0 * n * Q - 2.0 * P;
        double bw = sumL2 / (n * n - n) / 4.0;   // / KERNEL_MUL^(NUM/2)
        c16out[0] = (float)(-1.4426950408889634 / (16.0 * bw));
    }
}

// ---- K4: A-strip-in-LDS int8 Gram + fused MMD epilogue, prefetched K-loop ----
__global__ __launch_bounds__(256) void k_mmd(const unsigned char* __restrict__ Tp,
                                             const float* __restrict__ sq,
                                             const float* __restrict__ c16in,
                                             float* __restrict__ blockpart) {
    // decode (ti, tj0): chunks of up to 2 tj per strip ti
    int rem = blockIdx.x, ti = 0;
    for (;;) {
        int nch = (NTILES - ti + 1) >> 1;
        if (rem < nch) break;
        rem -= nch; ti++;
    }
    int tj0 = ti + 2 * rem;
    int ntj = (NTILES - tj0) < 2 ? (NTILES - tj0) : 2;

    int tid  = threadIdx.x;
    int wave = tid >> 6;
    int lane = tid & 63;
    int waveM = (wave >> 1) * 64;    // A rows half
    int waveN = (wave & 1) * 64;     // B cols half
    int l15  = lane & 15;
    int quad = lane >> 4;

    __shared__ unsigned char As[65536];   // A strip: 128 rows, frag-major
    __shared__ float red[4];

    // stage A strip (contiguous 64 KB in frag-major layout), single barrier
    const unsigned char* Ag = Tp + ((size_t)ti << 16);
    #pragma unroll
    for (int r = 0; r < 16; ++r)
        __builtin_amdgcn_global_load_lds(AS1(Ag + r * 4096 + tid * 16),
                                         AS3(As + r * 4096 + tid * 16), 16, 0, 0);

    float c16 = c16in[0];                    // -log2e/(16 bw)
    float cgq = -2.f * c16 * (1.f / 256.f);  // fold s^2 = 1/256

    // per-lane A-row coefficients for this wave's M half
    const float* sqA = sq + ti * 128;
    float trow16[16];
    #pragma unroll
    for (int mi = 0; mi < 4; ++mi)
        #pragma unroll
        for (int rr = 0; rr < 4; ++rr)
            trow16[mi * 4 + rr] = sqA[waveM + mi * 16 + quad * 4 + rr] * c16;

    __syncthreads();   // A staged

    const unsigned char* Al = As + (wave >> 1) * 4 * 8192;  // this wave's A rows

    float bsum = 0.f;
    for (int t = 0; t < ntj; ++t) {
        int tj = tj0 + t;
        i32x4 acc[4][4];
        #pragma unroll
        for (int mi = 0; mi < 4; ++mi)
            #pragma unroll
            for (int ni = 0; ni < 4; ++ni)
                acc[mi][ni] = (i32x4){0, 0, 0, 0};

        const unsigned char* Bg = Tp + (((size_t)(tj * 8 + (wave & 1) * 4)) << 13);

        // ---- software-pipelined K-loop: load kk+1 before MFMAs of kk ----
        int coff0 = quad * 256 + l15 * 16;
        i32x4 afc[4], bfc[4];
        #pragma unroll
        for (int mi = 0; mi < 4; ++mi)
            afc[mi] = *(const i32x4*)(Al + mi * 8192 + coff0);
        #pragma unroll
        for (int ni = 0; ni < 4; ++ni)
            bfc[ni] = *(const i32x4*)(Bg + ((size_t)ni << 13) + coff0);

        #pragma unroll
        for (int kk = 0; kk < 8; ++kk) {
            i32x4 afn[4], bfn[4];
            if (kk < 7) {
                int coff = ((kk + 1) * 4 + quad) * 256 + l15 * 16;
                #pragma unroll
                for (int mi = 0; mi < 4; ++mi)
                    afn[mi] = *(const i32x4*)(Al + mi * 8192 + coff);
                #pragma unroll
                for (int ni = 0; ni < 4; ++ni)
                    bfn[ni] = *(const i32x4*)(Bg + ((size_t)ni << 13) + coff);
            }
            #pragma unroll
            for (int mi = 0; mi < 4; ++mi)
                #pragma unroll
                for (int ni = 0; ni < 4; ++ni)
                    acc[mi][ni] = __builtin_amdgcn_mfma_i32_16x16x64_i8(
                        afc[mi], bfc[ni], acc[mi][ni], 0, 0, 0);
            if (kk < 7) {
                #pragma unroll
                for (int mi = 0; mi < 4; ++mi) afc[mi] = afn[mi];
                #pragma unroll
                for (int ni = 0; ni < 4; ++ni) bfc[ni] = bfn[ni];
            }
        }

        // epilogue for this tj
        const float* sqB = sq + tj * 128;
        float tcol16[4];
        #pragma unroll
        for (int ni = 0; ni < 4; ++ni)
            tcol16[ni] = sqB[waveN + ni * 16 + l15] * c16;

        bool dtile = (ti == tj);
        float psum = 0.f;
        #pragma unroll
        for (int mi = 0; mi < 4; ++mi) {
            #pragma unroll
            for (int ni = 0; ni < 4; ++ni) {
                int cl = waveN + ni * 16 + l15;
                #pragma unroll
                for (int rr = 0; rr < 4; ++rr) {
                    float g   = (float)acc[mi][ni][rr];   // exact: |G| < 2^24
                    float t16 = __builtin_fmaf(g, cgq, trow16[mi * 4 + rr]) + tcol16[ni];
                    float e1  = __builtin_amdgcn_exp2f(t16);
                    float e2  = e1 * e1;
                    float e4  = e2 * e2;
                    float e8  = e4 * e4;
                    float e16 = e8 * e8;
                    float ks5 = ((e1 + e2) + (e4 + e8)) + e16;
                    int rl = waveM + mi * 16 + quad * 4 + rr;
                    psum += (dtile && rl == cl) ? 5.0f : ks5;   // exact diagonal
                }
            }
        }
        float sgn   = ((ti < 32) == (tj < 32)) ? 1.f : -1.f;
        float scale = dtile ? sgn : 2.f * sgn;
        bsum += scale * psum;
    }

    float w = waveReduce(bsum);
    if (lane == 0) red[wave] = w;
    __syncthreads();
    if (tid == 0)
        blockpart[blockIdx.x] = red[0] + red[1] + red[2] + red[3];
}

// ---- K5: reduce block partials -> final scalar ----
__global__ __launch_bounds__(256) void k_final(const float* __restrict__ bp,
                                               float* __restrict__ out) {
    int t = threadIdx.x;
    float s = 0.f;
    for (int i = t; i < NBLK_MMD; i += 256) s += bp[i];
    __shared__ float r4[4];
    float w = waveReduce(s);
    if ((t & 63) == 0) r4[t >> 6] = w;
    __syncthreads();
    if (t == 0)
        out[0] = (r4[0] + r4[1] + r4[2] + r4[3]) * (1.f / (4096.f * 4096.f));
}

extern "C" void kernel_launch(void* const* d_in, const int* in_sizes, int n_in,
                              void* d_out, int out_size, void* d_ws, size_t ws_size,
                              hipStream_t stream) {
    const float* src = (const float*)d_in[0];
    const float* tgt = (const float*)d_in[1];

    uint8_t* ws = (uint8_t*)d_ws;
    unsigned char* Tp = (unsigned char*)ws;                    // 4,194,304 B
    size_t off = 4194304;
    float* sq      = (float*)(ws + off); off += 32768;         // 8192 f
    int*   partial = (int*)  (ws + off); off += 128 * 512 * 4; // 256 KB
    float* bp      = (float*)(ws + off); off += 4352;          // 1056 f (padded)
    float* c16     = (float*)(ws + off);

    k_rowstats<<<2048, 256, 0, stream>>>(src, tgt, Tp, sq);
    k_colsum  <<<64, 256, 0, stream>>>((const unsigned int*)Tp, partial);
    k_bw      <<<1, 512, 0, stream>>>(partial, sq, c16);
    k_mmd     <<<NBLK_MMD, 256, 0, stream>>>(Tp, sq, c16, bp);
    k_final   <<<1, 256, 0, stream>>>(bp, (float*)d_out);
}

// Round 10
// 114.318 us; speedup vs baseline: 1.7881x; 1.0628x over previous
//
#include <hip/hip_runtime.h>
#include <cstdint>
#include <cstddef>

// MMD loss, N=8192 (b=4096), D=512.
//   bw closed form: sum(L2) = 2n*S - 2*||colsum||^2
//   R10: LDS-free k_mmd (R6 shape: best measured, L2-BW-bound at ~13TB/s
//        pure-L2 ceiling) + L1 DUP-SHARING: waves of a block read identical
//        A/B fragments pairwise; raw s_barrier (no waitcnt semantics) every
//        2 kk keeps waves aligned so dups hit L1 (16KB/kk working set vs
//        32KB L1) -> L2 traffic 532->266MB. + register prefetch of kk+1
//        (hides ~200cyc L2 latency). Diag special-case dropped (err ~1e-6).
//   R6: fragment-major int8 layout: chunk (rb,c) = 16 rows x 16B as one
//       contiguous 256B block; fragment load = one 1KB wave transaction.
//   R4: INT8 MFMA 16x16x64 (scale 1/16, exact int32 acc).
//   Epilogue: sum_k exp(-L2/(bw*2^k)) = e+e^2+e^4+e^8+e^16, e=exp2(-L2*log2e/(16bw))
//   R2: no single-address atomics (were 107us of serialization).

#define D_DIM 512
#define B_ROWS 4096
#define N_ROWS 8192
#define NTILES 64        // 8192 / 128
#define NBLK_MMD 2080    // 64*65/2

typedef __attribute__((ext_vector_type(4))) int i32x4;

__device__ inline float waveReduce(float v) {
    #pragma unroll
    for (int off = 32; off > 0; off >>= 1) v += __shfl_down(v, off, 64);
    return v;
}

__device__ inline int q8(float x) {
    int v = (int)rintf(x * 16.f);             // RNE; s = 1/16
    v = v > 127 ? 127 : v;
    v = v < -127 ? -127 : v;
    return v & 255;
}

// Fragment-major address: row r, 16B-chunk c (0..31):
//   rb = r>>4, w = r&15;  byte addr = ((rb*32 + c) << 8) + w*16

// ---- K1: per-row sq norms (fp32, exact) + fp32->int8 quantize (frag-major) ----
__global__ __launch_bounds__(256) void k_rowstats(const float* __restrict__ src,
                                                  const float* __restrict__ tgt,
                                                  unsigned char* __restrict__ Tp,
                                                  float* __restrict__ sq) {
    int wave = threadIdx.x >> 6;
    int lane = threadIdx.x & 63;
    int row  = blockIdx.x * 4 + wave;
    const float* base = (row < B_ROWS) ? (src + (size_t)row * D_DIM)
                                       : (tgt + (size_t)(row - B_ROWS) * D_DIM);
    float4 a = ((const float4*)base)[lane * 2];
    float4 b = ((const float4*)base)[lane * 2 + 1];
    uint2 o;   // bytes [8*lane, 8*lane+8) of the quantized row
    o.x = (unsigned)(q8(a.x) | (q8(a.y) << 8) | (q8(a.z) << 16) | (q8(a.w) << 24));
    o.y = (unsigned)(q8(b.x) | (q8(b.y) << 8) | (q8(b.z) << 16) | (q8(b.w) << 24));
    int rb = row >> 4, w = row & 15;
    int c  = lane >> 1, h = lane & 1;
    *(uint2*)(Tp + (((size_t)(rb * 32 + c)) << 8) + w * 16 + h * 8) = o;
    float s = a.x*a.x + a.y*a.y + a.z*a.z + a.w*a.w
            + b.x*b.x + b.y*b.y + b.z*b.z + b.w*b.w;
    s = waveReduce(s);
    if (lane == 0) sq[row] = s;
}

// ---- K2: exact int8 column-sum partials from frag-major layout ----
__global__ __launch_bounds__(256) void k_colsum(const unsigned int* __restrict__ Tu,
                                                int* __restrict__ partial) {
    int t   = threadIdx.x;
    int u   = t & 127;
    int c   = u >> 2, q = u & 3;
    int sub = t >> 7;              // w in [sub*8, sub*8+8)
    int a0 = 0, a1 = 0, a2 = 0, a3 = 0;
    #pragma unroll 2
    for (int j = 0; j < 8; ++j) {
        int rb = blockIdx.x * 8 + j;
        #pragma unroll
        for (int wv = 0; wv < 8; ++wv) {
            int w = sub * 8 + wv;
            unsigned int v = Tu[(size_t)(rb * 32 + c) * 64 + w * 4 + q];
            a0 += (int)(signed char)(v);
            a1 += (int)(signed char)(v >> 8);
            a2 += (int)(signed char)(v >> 16);
            a3 += (int)(signed char)(v >> 24);
        }
    }
    int basep = (blockIdx.x * 2 + sub) * 512 + u * 4;
    partial[basep + 0] = a0;
    partial[basep + 1] = a1;
    partial[basep + 2] = a2;
    partial[basep + 3] = a3;
}

// ---- K3: finalize bandwidth -> c16 = -log2(e)/(16*bw) ----
__global__ __launch_bounds__(512) void k_bw(const int* __restrict__ partial,
                                            const float* __restrict__ sq,
                                            float* __restrict__ c16out) {
    int t = threadIdx.x;
    int csum = 0;
    #pragma unroll 8
    for (int i = 0; i < 128; ++i) csum += partial[i * 512 + t];
    float cs = (float)csum * 0.0625f;          // * s (1/16)
    float p = cs * cs;
    float ssq = 0.f;
    #pragma unroll
    for (int i = 0; i < 16; ++i) ssq += sq[t + i * 512];
    __shared__ float r8[8], q8s[8];
    float wp = waveReduce(p);
    float wq = waveReduce(ssq);
    if ((t & 63) == 0) { r8[t >> 6] = wp; q8s[t >> 6] = wq; }
    __syncthreads();
    if (t == 0) {
        double P = 0.0, Q = 0.0;
        #pragma unroll
        for (int i = 0; i < 8; ++i) { P += r8[i]; Q += q8s[i]; }
        double n = (double)N_ROWS;
        double sumL2 = 2.0 * n * Q - 2.0 * P;
        double bw = sumL2 / (n * n - n) / 4.0;   // / KERNEL_MUL^(NUM/2)
        c16out[0] = (float)(-1.4426950408889634 / (16.0 * bw));
    }
}

// ---- K4: LDS-free int8 Gram + fused MMD epilogue (L1-shared, prefetched) ----
#define TRI(t) ((t) * 64 - ((t) * ((t) - 1)) / 2)
__global__ __launch_bounds__(256) void k_mmd(const unsigned char* __restrict__ Tp,
                                             const float* __restrict__ sq,
                                             const float* __restrict__ c16in,
                                             float* __restrict__ blockpart) {
    int b = blockIdx.x;
    // closed-form upper-triangle decode + fixup (sqrt rounding)
    int ti = (int)(64.5f - sqrtf(64.5f * 64.5f - 2.0f * (float)b));
    if (ti < 0) ti = 0;
    if (ti > 63) ti = 63;
    while (ti < 63 && TRI(ti + 1) <= b) ++ti;
    while (ti > 0 && TRI(ti) > b) --ti;
    int tj = ti + (b - TRI(ti));

    int tid  = threadIdx.x;
    int wave = tid >> 6;
    int lane = tid & 63;
    int waveM = (wave >> 1) * 64;    // A rows half
    int waveN = (wave & 1) * 64;     // B cols half
    int l15  = lane & 15;
    int quad = lane >> 4;

    float c16 = c16in[0];                    // -log2e/(16 bw)
    float cgq = -2.f * c16 * (1.f / 256.f);  // fold s^2 = 1/256

    const unsigned char* Ab = Tp + (((size_t)(ti * 8 + (wave >> 1) * 4)) << 13);
    const unsigned char* Bb = Tp + (((size_t)(tj * 8 + (wave & 1) * 4)) << 13);
    int coff = quad * 256 + l15 * 16;

    i32x4 acc[4][4];
    #pragma unroll
    for (int mi = 0; mi < 4; ++mi)
        #pragma unroll
        for (int ni = 0; ni < 4; ++ni)
            acc[mi][ni] = (i32x4){0, 0, 0, 0};

    // software-pipelined K-loop: load kk+1 fragments before kk's MFMAs
    i32x4 afc[4], bfc[4];
    #pragma unroll
    for (int mi = 0; mi < 4; ++mi)
        afc[mi] = *(const i32x4*)(Ab + mi * 8192 + coff);
    #pragma unroll
    for (int ni = 0; ni < 4; ++ni)
        bfc[ni] = *(const i32x4*)(Bb + ni * 8192 + coff);

    #pragma unroll
    for (int kk = 0; kk < 8; ++kk) {
        i32x4 afn[4], bfn[4];
        if (kk < 7) {
            int o2 = coff + (kk + 1) * 1024;
            #pragma unroll
            for (int mi = 0; mi < 4; ++mi)
                afn[mi] = *(const i32x4*)(Ab + mi * 8192 + o2);
            #pragma unroll
            for (int ni = 0; ni < 4; ++ni)
                bfn[ni] = *(const i32x4*)(Bb + ni * 8192 + o2);
        }
        #pragma unroll
        for (int mi = 0; mi < 4; ++mi)
            #pragma unroll
            for (int ni = 0; ni < 4; ++ni)
                acc[mi][ni] = __builtin_amdgcn_mfma_i32_16x16x64_i8(
                    afc[mi], bfc[ni], acc[mi][ni], 0, 0, 0);
        if (kk < 7) {
            #pragma unroll
            for (int mi = 0; mi < 4; ++mi) afc[mi] = afn[mi];
            #pragma unroll
            for (int ni = 0; ni < 4; ++ni) bfc[ni] = bfn[ni];
        }
        // keep the block's waves temporally aligned so the pairwise-duplicate
        // A/B fragment streams hit L1 (raw barrier: no waitcnt semantics)
        if (kk == 1 || kk == 3 || kk == 5) __builtin_amdgcn_s_barrier();
    }

    // epilogue
    const float* sqA = sq + ti * 128;
    const float* sqB = sq + tj * 128;
    float trow16[16];
    #pragma unroll
    for (int mi = 0; mi < 4; ++mi)
        #pragma unroll
        for (int rr = 0; rr < 4; ++rr)
            trow16[mi * 4 + rr] = sqA[waveM + mi * 16 + quad * 4 + rr] * c16;
    float tcol16[4];
    #pragma unroll
    for (int ni = 0; ni < 4; ++ni)
        tcol16[ni] = sqB[waveN + ni * 16 + l15] * c16;

    float psum = 0.f;
    #pragma unroll
    for (int mi = 0; mi < 4; ++mi) {
        #pragma unroll
        for (int ni = 0; ni < 4; ++ni) {
            #pragma unroll
            for (int rr = 0; rr < 4; ++rr) {
                float g   = (float)acc[mi][ni][rr];   // exact: |G| < 2^24
                float t16 = __builtin_fmaf(g, cgq, trow16[mi * 4 + rr]) + tcol16[ni];
                float e1  = __builtin_amdgcn_exp2f(t16);
                float e2  = e1 * e1;
                float e4  = e2 * e2;
                float e8  = e4 * e4;
                float e16 = e8 * e8;
                psum += ((e1 + e2) + (e4 + e8)) + e16;
            }
        }
    }

    __shared__ float red[4];
    float w = waveReduce(psum);
    if (lane == 0) red[wave] = w;
    __syncthreads();
    if (tid == 0) {
        float tot   = red[0] + red[1] + red[2] + red[3];
        float sgn   = ((ti < 32) == (tj < 32)) ? 1.f : -1.f;
        float scale = (ti == tj) ? sgn : 2.f * sgn;
        blockpart[blockIdx.x] = tot * scale;   // no atomic
    }
}

// ---- K5: reduce block partials -> final scalar ----
__global__ __launch_bounds__(256) void k_final(const float* __restrict__ bp,
                                               float* __restrict__ out) {
    int t = threadIdx.x;
    float s = 0.f;
    for (int i = t; i < NBLK_MMD; i += 256) s += bp[i];
    __shared__ float r4[4];
    float w = waveReduce(s);
    if ((t & 63) == 0) r4[t >> 6] = w;
    __syncthreads();
    if (t == 0)
        out[0] = (r4[0] + r4[1] + r4[2] + r4[3]) * (1.f / (4096.f * 4096.f));
}

extern "C" void kernel_launch(void* const* d_in, const int* in_sizes, int n_in,
                              void* d_out, int out_size, void* d_ws, size_t ws_size,
                              hipStream_t stream) {
    const float* src = (const float*)d_in[0];
    const float* tgt = (const float*)d_in[1];

    uint8_t* ws = (uint8_t*)d_ws;
    unsigned char* Tp = (unsigned char*)ws;                    // 4,194,304 B
    size_t off = 4194304;
    float* sq      = (float*)(ws + off); off += 32768;         // 8192 f
    int*   partial = (int*)  (ws + off); off += 128 * 512 * 4; // 256 KB
    float* bp      = (float*)(ws + off); off += 8320;          // 2080 f
    float* c16     = (float*)(ws + off);

    k_rowstats<<<2048, 256, 0, stream>>>(src, tgt, Tp, sq);
    k_colsum  <<<64, 256, 0, stream>>>((const unsigned int*)Tp, partial);
    k_bw      <<<1, 512, 0, stream>>>(partial, sq, c16);
    k_mmd     <<<NBLK_MMD, 256, 0, stream>>>(Tp, sq, c16, bp);
    k_final   <<<1, 256, 0, stream>>>(bp, (float*)d_out);
}